// Round 1
// baseline (55.882 us; speedup 1.0000x reference)
//
#include <hip/hip_runtime.h>
#include <math.h>

#define HIDDEN 1024
#define VOCAB  50257
#define MAXLEN 64

__device__ __forceinline__ float wave_reduce_sum(float v) {
    #pragma unroll
    for (int off = 32; off > 0; off >>= 1)
        v += __shfl_down(v, off, 64);
    return v;
}

// 64 blocks x 256 threads: scores[m] = dot(concat(emb_row, h0), attn_W[m]) + attn_b[m]
__global__ void k_scores(const int* __restrict__ token,
                         const float* __restrict__ emb,
                         const float* __restrict__ hidden,
                         const float* __restrict__ attn_W,
                         const float* __restrict__ attn_b,
                         float* __restrict__ ws_scores) {
    const int m = blockIdx.x;
    const int t = threadIdx.x;
    const float* erow = emb + (size_t)token[0] * HIDDEN;
    const float4* Wrow = (const float4*)(attn_W + (size_t)m * 2 * HIDDEN);
    float acc = 0.f;
    #pragma unroll
    for (int it = 0; it < 2; ++it) {
        int i = t + it * 256;            // 0..511 float4s
        float4 w4 = Wrow[i];
        int k = i * 4;
        const float* src = (k < HIDDEN) ? (erow + k) : (hidden + k - HIDDEN);
        float4 c4 = *(const float4*)src;
        acc += w4.x * c4.x + w4.y * c4.y + w4.z * c4.z + w4.w * c4.w;
    }
    __shared__ float part[4];
    acc = wave_reduce_sum(acc);
    const int wid = t >> 6, lane = t & 63;
    if (lane == 0) part[wid] = acc;
    __syncthreads();
    if (t == 0)
        ws_scores[m] = part[0] + part[1] + part[2] + part[3] + attn_b[m];
}

// 1 block x 64 threads: softmax over 64 scores
__global__ void k_softmax(const float* __restrict__ ws_scores,
                          float* __restrict__ ws_w,
                          float* __restrict__ out_attn) {
    const int l = threadIdx.x;
    float s = ws_scores[l];
    float m = s;
    #pragma unroll
    for (int off = 32; off > 0; off >>= 1) m = fmaxf(m, __shfl_xor(m, off, 64));
    float e = expf(s - m);
    float sum = e;
    #pragma unroll
    for (int off = 32; off > 0; off >>= 1) sum += __shfl_xor(sum, off, 64);
    float w = e / sum;
    ws_w[l] = w;
    out_attn[l] = w;
}

// 4 blocks x 256 threads: ctx[h] = sum_m w[m] * enc[m][h]
__global__ void k_context(const float* __restrict__ ws_w,
                          const float* __restrict__ enc,
                          float* __restrict__ ws_ctx) {
    __shared__ float w[MAXLEN];
    const int t = threadIdx.x;
    if (t < MAXLEN) w[t] = ws_w[t];
    __syncthreads();
    const int h = blockIdx.x * 256 + t;
    float acc = 0.f;
    #pragma unroll 8
    for (int m = 0; m < MAXLEN; ++m)
        acc += w[m] * enc[(size_t)m * HIDDEN + h];
    ws_ctx[h] = acc;
}

// 256 blocks x 256 threads (wave per row): x[j] = relu(dot(concat(emb_row, ctx), comb_W[j]) + comb_b[j])
__global__ void k_combine(const int* __restrict__ token,
                          const float* __restrict__ emb,
                          const float* __restrict__ ws_ctx,
                          const float* __restrict__ comb_W,
                          const float* __restrict__ comb_b,
                          float* __restrict__ ws_x) {
    const int wid = threadIdx.x >> 6, lane = threadIdx.x & 63;
    const int j = blockIdx.x * 4 + wid;
    const float* erow = emb + (size_t)token[0] * HIDDEN;
    const float4* Wrow = (const float4*)(comb_W + (size_t)j * 2 * HIDDEN);
    float acc = 0.f;
    #pragma unroll
    for (int it = 0; it < 8; ++it) {
        int i = lane + it * 64;          // 0..511 float4s
        float4 w4 = Wrow[i];
        int k = i * 4;
        const float* src = (k < HIDDEN) ? (erow + k) : (ws_ctx + k - HIDDEN);
        float4 c4 = *(const float4*)src;
        acc += w4.x * c4.x + w4.y * c4.y + w4.z * c4.z + w4.w * c4.w;
    }
    acc = wave_reduce_sum(acc);
    if (lane == 0) ws_x[j] = fmaxf(acc + comb_b[j], 0.f);
}

// 256 blocks x 256 threads (wave per j): GRU gate math -> h_new[j]
__global__ void k_gru(const float* __restrict__ ws_x,
                      const float* __restrict__ hidden,
                      const float* __restrict__ W_ih,
                      const float* __restrict__ W_hh,
                      const float* __restrict__ b_ih,
                      const float* __restrict__ b_hh,
                      float* __restrict__ ws_h,
                      float* __restrict__ out_h) {
    const int wid = threadIdx.x >> 6, lane = threadIdx.x & 63;
    const int j = blockIdx.x * 4 + wid;
    float d[6];
    const float* rows[6] = {
        W_ih + (size_t)j * HIDDEN,
        W_ih + (size_t)(j + HIDDEN) * HIDDEN,
        W_ih + (size_t)(j + 2 * HIDDEN) * HIDDEN,
        W_hh + (size_t)j * HIDDEN,
        W_hh + (size_t)(j + HIDDEN) * HIDDEN,
        W_hh + (size_t)(j + 2 * HIDDEN) * HIDDEN };
    const float* vecs[2] = { ws_x, hidden };
    #pragma unroll
    for (int q = 0; q < 6; ++q) {
        const float4* W4 = (const float4*)rows[q];
        const float4* v4 = (const float4*)vecs[q / 3];
        float acc = 0.f;
        #pragma unroll
        for (int it = 0; it < 4; ++it) {
            int i = lane + it * 64;      // 0..255 float4s
            float4 a = W4[i];
            float4 b = v4[i];
            acc += a.x * b.x + a.y * b.y + a.z * b.z + a.w * b.w;
        }
        d[q] = wave_reduce_sum(acc);
    }
    if (lane == 0) {
        float i_r = d[0] + b_ih[j];
        float i_z = d[1] + b_ih[j + HIDDEN];
        float i_n = d[2] + b_ih[j + 2 * HIDDEN];
        float h_r = d[3] + b_hh[j];
        float h_z = d[4] + b_hh[j + HIDDEN];
        float h_n = d[5] + b_hh[j + 2 * HIDDEN];
        float r = 1.f / (1.f + expf(-(i_r + h_r)));
        float z = 1.f / (1.f + expf(-(i_z + h_z)));
        float n = tanhf(i_n + r * h_n);
        float h0v = hidden[j];
        float hn = (1.f - z) * n + z * h0v;
        ws_h[j] = hn;
        out_h[j] = hn;
    }
}

// ceil(VOCAB/4) blocks x 256 threads (wave per vocab row): logits[v] = dot(h_new, out_W[v]) + out_b[v]
__global__ void k_logits(const float* __restrict__ ws_h,
                         const float* __restrict__ out_W,
                         const float* __restrict__ out_b,
                         float* __restrict__ out_logits) {
    __shared__ float4 hn[HIDDEN / 4];
    const int t = threadIdx.x;
    hn[t] = ((const float4*)ws_h)[t];
    __syncthreads();
    const int wid = t >> 6, lane = t & 63;
    const int v = blockIdx.x * 4 + wid;
    if (v >= VOCAB) return;
    const float4* Wrow = (const float4*)(out_W + (size_t)v * HIDDEN);
    float acc = 0.f;
    #pragma unroll
    for (int i = 0; i < 4; ++i) {
        float4 a = Wrow[lane + i * 64];
        float4 b = hn[lane + i * 64];
        acc += a.x * b.x + a.y * b.y + a.z * b.z + a.w * b.w;
    }
    acc = wave_reduce_sum(acc);
    if (lane == 0) out_logits[v] = acc + out_b[v];
}

extern "C" void kernel_launch(void* const* d_in, const int* in_sizes, int n_in,
                              void* d_out, int out_size, void* d_ws, size_t ws_size,
                              hipStream_t stream) {
    const int*   token  = (const int*)d_in[0];
    const float* hidden = (const float*)d_in[1];
    const float* enc    = (const float*)d_in[2];
    const float* emb    = (const float*)d_in[3];
    const float* attn_W = (const float*)d_in[4];
    const float* attn_b = (const float*)d_in[5];
    const float* comb_W = (const float*)d_in[6];
    const float* comb_b = (const float*)d_in[7];
    const float* W_ih   = (const float*)d_in[8];
    const float* W_hh   = (const float*)d_in[9];
    const float* b_ih   = (const float*)d_in[10];
    const float* b_hh   = (const float*)d_in[11];
    const float* out_W  = (const float*)d_in[12];
    const float* out_b  = (const float*)d_in[13];

    float* out = (float*)d_out;
    float* out_logits = out;                       // [50257]
    float* out_h      = out + VOCAB;               // [1024]
    float* out_attn   = out + VOCAB + HIDDEN;      // [64]

    float* ws = (float*)d_ws;
    float* ws_scores = ws;            // 64
    float* ws_w      = ws + 64;       // 64
    float* ws_ctx    = ws + 128;      // 1024
    float* ws_x      = ws + 1152;     // 1024
    float* ws_h      = ws + 2176;     // 1024

    k_scores<<<MAXLEN, 256, 0, stream>>>(token, emb, hidden, attn_W, attn_b, ws_scores);
    k_softmax<<<1, 64, 0, stream>>>(ws_scores, ws_w, out_attn);
    k_context<<<HIDDEN / 256, 256, 0, stream>>>(ws_w, enc, ws_ctx);
    k_combine<<<HIDDEN / 4, 256, 0, stream>>>(token, emb, ws_ctx, comb_W, comb_b, ws_x);
    k_gru<<<HIDDEN / 4, 256, 0, stream>>>(ws_x, hidden, W_ih, W_hh, b_ih, b_hh, ws_h, out_h);
    k_logits<<<(VOCAB + 3) / 4, 256, 0, stream>>>(ws_h, out_W, out_b, out_logits);
}